// Round 6
// baseline (262.754 us; speedup 1.0000x reference)
//
#include <hip/hip_runtime.h>

#define S_DEPTH 256
#define NRES 384
#define CIN 32
#define CZ 128
#define MDIM (NRES * CIN) /* 12288 */

typedef short bf16x8 __attribute__((ext_vector_type(8)));
typedef short short4v __attribute__((ext_vector_type(4)));
typedef float f32x4 __attribute__((ext_vector_type(4)));

static __device__ __forceinline__ unsigned short f2bf(float f) {
  unsigned int u = __float_as_uint(f);
  unsigned int r = (u + 0x7fffu + ((u >> 16) & 1u)) >> 16; // RNE
  return (unsigned short)r;
}

static __device__ __forceinline__ void gld16(const void* g, void* l) {
  __builtin_amdgcn_global_load_lds((__attribute__((address_space(1))) void*)(g),
                                   (__attribute__((address_space(3))) void*)(l),
                                   16, 0, 0);
}

// ---------------- fused pre-kernel (R0 version) ----------------
__global__ __launch_bounds__(256) void k_pre(
    const float* __restrict__ mm, const float* __restrict__ gamma,
    const float* __restrict__ beta, const float* __restrict__ W1,
    const float* __restrict__ W2, const float* __restrict__ W3,
    unsigned short* __restrict__ aT, unsigned short* __restrict__ bT,
    unsigned short* __restrict__ W3T) {
  __shared__ __align__(16) char sraw[256 * 33 * 4];
  const int t = threadIdx.x;

  if (blockIdx.x < 16) {
    unsigned short (*tile)[72] = (unsigned short(*)[72])sraw; // [128][72]
    const int b = blockIdx.x;
    const int d0 = (b & 7) * 4;
    const int e0 = (b >> 3) * 64;
#pragma unroll
    for (int iter = 0; iter < 32; ++iter) {
      int lr_ = iter * 4 + (t >> 6);
      int c = lr_ >> 2, dl = lr_ & 3;
      int q = c * 32 + d0 + dl;
      tile[lr_][t & 63] = f2bf(W3[q * 128 + e0 + (t & 63)]);
    }
    __syncthreads();
    const int e_l = t >> 2;
    const int dl = t & 3;
    unsigned short* dst = W3T + (((size_t)(d0 + dl) * 128) + e0 + e_l) * 32;
#pragma unroll
    for (int j = 0; j < 32; ++j) dst[j] = tile[j * 4 + dl][e_l];
    return;
  }

  float* buf = (float*)sraw; // [256][33]
  const int i = blockIdx.x - 16;

#pragma unroll
  for (int it = 0; it < 8; ++it) {
    int s = it * 32 + (t >> 3);
    int c4 = (t & 7) * 4;
    const float4 v = *(const float4*)(mm + ((size_t)s * NRES + i) * CIN + c4);
    buf[s * 33 + c4 + 0] = v.x;
    buf[s * 33 + c4 + 1] = v.y;
    buf[s * 33 + c4 + 2] = v.z;
    buf[s * 33 + c4 + 3] = v.w;
  }
  __syncthreads();

  float x[32];
#pragma unroll
  for (int k = 0; k < 32; ++k) x[k] = buf[t * 33 + k];
  float mu = 0.f;
#pragma unroll
  for (int k = 0; k < 32; ++k) mu += x[k];
  mu *= (1.f / 32.f);
  float var = 0.f;
#pragma unroll
  for (int k = 0; k < 32; ++k) {
    float dk = x[k] - mu;
    var += dk * dk;
  }
  var *= (1.f / 32.f);
  float inv = rsqrtf(var + 1e-5f);
#pragma unroll
  for (int k = 0; k < 32; ++k) x[k] = (x[k] - mu) * inv * gamma[k] + beta[k];

  float va[32], vb[32];
#pragma unroll
  for (int c = 0; c < 32; ++c) { va[c] = 0.f; vb[c] = 0.f; }
#pragma unroll
  for (int k = 0; k < 32; ++k) {
    float xk = x[k];
#pragma unroll
    for (int c = 0; c < 32; ++c) va[c] += xk * W1[k * 32 + c];
#pragma unroll
    for (int c = 0; c < 32; ++c) vb[c] += xk * W2[k * 32 + c];
  }

  unsigned short* dstA = aT + ((size_t)(t >> 6) * MDIM + (size_t)i * 32) * 64 + (t & 63);
  unsigned short* dstB = bT + ((size_t)(t >> 6) * MDIM + (size_t)i * 32) * 64 + (t & 63);
#pragma unroll
  for (int c = 0; c < 32; ++c) dstA[c * 64] = f2bf(va[c]);
#pragma unroll
  for (int c = 0; c < 32; ++c) dstB[c * 64] = f2bf(vb[c]);
}

// ---------------- kernel 2: 256x256 o-tile, 512 threads, fused W3 epilogue ----
// R6: R4 winner (dbuf main, 256x256, 1 blk/CU = LDS-pipe-bound per budget:
// LDS ~29.6k cyc/round vs MFMA 12.4k) with epilogue re-decomposed:
//   wave = (e-half eh, kq-quarter kh). o_lds read 2x total (256KB/block, was
//   8x = 1MB); W3T still read exactly once/block (R3 lesson). Partials (f32,
//   8 x 16KB = 128KB, exactly smem) reduced via one extra sync: every wave
//   writes its partial, then wave (eh,rq) sums 4 partials for 16 rows x 64 e
//   and stores. Net LDS save ~6-7k cyc/round.
__global__ __launch_bounds__(512, 2) void k_opm(
    const unsigned short* __restrict__ aT, const unsigned short* __restrict__ bT,
    const unsigned short* __restrict__ W3T, const float* __restrict__ b3,
    float* __restrict__ out) {
  __shared__ __align__(16) char smem[131072]; // 2x(A32K+B32K) staging; o_lds/partials 128KB
  const int t = threadIdx.x;
  const int w = t >> 6;  // wave 0..7
  const int l = t & 63;
  const int lr = l & 15;
  const int quad = l >> 4;
  const int wm = w >> 2, wn = w & 3;

  const int g = blockIdx.x;
  const int xcd = g & 7;
  const int rr = g >> 3;                   // 0..287
  const int bx = rr / 6;                   // 0..47
  const int by = xcd * 6 + (rr - bx * 6);  // 0..47
  const int m0 = by * 256;
  const int n0 = bx * 256;

  f32x4 acc[8][4];
#pragma unroll
  for (int mt = 0; mt < 8; ++mt)
#pragma unroll
    for (int nt = 0; nt < 4; ++nt) {
      acc[mt][nt][0] = 0.f; acc[mt][nt][1] = 0.f;
      acc[mt][nt][2] = 0.f; acc[mt][nt][3] = 0.f;
    }

  // lane offset inside a 1KB chunk (8 rows x 128B), XOR k-seg swizzle
  const int laneoff = (l >> 3) * 64 + (((l & 7) ^ (l >> 3)) * 8);
  const int r8 = lr & 7;

  // ---- 2-phase pipelined main loop over 4 k-slices of 64 (R4 verified) ----
  {
    const unsigned short* aS = aT + (size_t)m0 * 64;
    const unsigned short* bS = bT + (size_t)n0 * 64;
#pragma unroll
    for (int p_ = 0; p_ < 4; ++p_) {
      int ch = p_ * 8 + w;
      gld16(aS + ch * 512 + laneoff, smem + ch * 1024);
      gld16(bS + ch * 512 + laneoff, smem + 32768 + ch * 1024);
    }
  }
  __syncthreads();

  for (int kt = 0; kt < 4; ++kt) {
    if (kt < 3) {  // issue next-slice loads into the other buffer
      char* nb = smem + ((kt + 1) & 1) * 65536;
      const unsigned short* aS = aT + ((size_t)(kt + 1) * MDIM + m0) * 64;
      const unsigned short* bS = bT + ((size_t)(kt + 1) * MDIM + n0) * 64;
#pragma unroll
      for (int p_ = 0; p_ < 4; ++p_) {
        int ch = p_ * 8 + w;
        gld16(aS + ch * 512 + laneoff, nb + ch * 1024);
        gld16(bS + ch * 512 + laneoff, nb + 32768 + ch * 1024);
      }
    }
    const char* cb = smem + (kt & 1) * 65536;
    const char* cbB = cb + 32768;

#pragma unroll
    for (int ks = 0; ks < 2; ++ks) {
      const int segoff = (((ks * 4 + quad) ^ r8) << 4);
      bf16x8 af[8];
#pragma unroll
      for (int mt = 0; mt < 8; ++mt) {
        int chunk = wm * 16 + mt * 2 + (lr >> 3);
        af[mt] = *(const bf16x8*)(cb + chunk * 1024 + r8 * 128 + segoff);
      }
#pragma unroll
      for (int nt = 0; nt < 4; ++nt) {
        int chunk = wn * 8 + nt * 2 + (lr >> 3);
        bf16x8 bfr = *(const bf16x8*)(cbB + chunk * 1024 + r8 * 128 + segoff);
#pragma unroll
        for (int mt = 0; mt < 8; ++mt)
          acc[mt][nt] =
              __builtin_amdgcn_mfma_f32_16x16x32_bf16(af[mt], bfr, acc[mt][nt], 0, 0, 0);
      }
    }
    __syncthreads();  // next-tile DMA has the full compute phase to land
  }

  // ---- repack o (bf16, /256) into o_lds[64 p][1024 q'] XOR-swizzled (R4) ----
  const float scale = 1.0f / 256.0f;
#pragma unroll
  for (int mt = 0; mt < 8; ++mt) {
    int i_l = wm * 4 + (mt >> 1);
    int chc = 2 * (mt & 1) + (quad >> 1); // c0>>3, c0 = (mt&1)*16 + quad*4
#pragma unroll
    for (int nt = 0; nt < 4; ++nt) {
      int j_l = wn * 2 + (nt >> 1);
      int d = (nt & 1) * 16 + lr;
      int p = i_l * 8 + j_l;
      int ch = d * 4 + chc;
      int key = (p ^ d) & 7;
      int off = p * 2048 + ((ch ^ key) << 4) + 8 * (quad & 1);
      short4v pk;
      pk[0] = (short)f2bf(acc[mt][nt][0] * scale);
      pk[1] = (short)f2bf(acc[mt][nt][1] * scale);
      pk[2] = (short)f2bf(acc[mt][nt][2] * scale);
      pk[3] = (short)f2bf(acc[mt][nt][3] * scale);
      *(short4v*)(smem + off) = pk;
    }
  }
  __syncthreads();

  // ---- epilogue v2: wave (eh = w>>2, kh = w&3) computes PARTIAL z over all
  //      64 rows for e in [eh*64, eh*64+64), kq in [kh*8, kh*8+8).
  const int eh = w >> 2;
  const int kh = w & 3;

  f32x4 zacc[4][4]; // [row-group mte][e-group ne]
#pragma unroll
  for (int a = 0; a < 4; ++a)
#pragma unroll
    for (int b_ = 0; b_ < 4; ++b_) {
      zacc[a][b_][0] = 0.f; zacc[a][b_][1] = 0.f;
      zacc[a][b_][2] = 0.f; zacc[a][b_][3] = 0.f;
    }

#pragma unroll
  for (int kq8 = 0; kq8 < 8; ++kq8) {
    const int kq = kh * 8 + kq8;
    bf16x8 aef[4];
#pragma unroll
    for (int mte = 0; mte < 4; ++mte) {
      int row = mte * 16 + lr;
      int ch = kq * 4 + quad;
      int key = (row ^ kq) & 7;
      aef[mte] = *(const bf16x8*)(smem + row * 2048 + ((ch ^ key) << 4));
    }
#pragma unroll
    for (int ne = 0; ne < 4; ++ne) {
      bf16x8 wf = *(const bf16x8*)(W3T + (size_t)kq * 4096 +
                                   (size_t)(eh * 64 + ne * 16 + lr) * 32 + quad * 8);
#pragma unroll
      for (int mte = 0; mte < 4; ++mte)
        zacc[mte][ne] =
            __builtin_amdgcn_mfma_f32_16x16x32_bf16(aef[mte], wf, zacc[mte][ne], 0, 0, 0);
    }
  }

  // ---- write partials: region w*16KB, layout [ec 64][p-swz 64] f32 ----
  __syncthreads();  // all o_lds reads done; partials overwrite o_lds
  {
    char* pb = smem + w * 16384;
#pragma unroll
    for (int mte = 0; mte < 4; ++mte) {
      int p4 = mte * 16 + quad * 4;
#pragma unroll
      for (int ne = 0; ne < 4; ++ne) {
        int ec = ne * 16 + lr;
        int pw = p4 ^ ((ec & 7) << 3);  // preserves low 2 bits (f32x4 contig)
        *(f32x4*)(pb + (ec * 64 + pw) * 4) = zacc[mte][ne];
      }
    }
  }
  __syncthreads();

  // ---- reduce 4 kq-partials + bias + store: wave (eh2 = w>>2, rq = w&3)
  //      handles rows rq*16..+15, e-half eh2.
  const int eh2 = w >> 2;
  const int rq = w & 3;
  const int i0 = by * 8, j0 = bx * 8;
#pragma unroll
  for (int ecg = 0; ecg < 4; ++ecg) {
    int ec = ecg * 16 + lr;
    int p4 = rq * 16 + quad * 4;
    int pw = p4 ^ ((ec & 7) << 3);
    size_t slot = (size_t)(ec * 64 + pw) * 4;
    f32x4 sum = *(const f32x4*)(smem + (size_t)(eh2 * 4 + 0) * 16384 + slot);
#pragma unroll
    for (int kh2 = 1; kh2 < 4; ++kh2) {
      f32x4 v = *(const f32x4*)(smem + (size_t)(eh2 * 4 + kh2) * 16384 + slot);
      sum[0] += v[0]; sum[1] += v[1]; sum[2] += v[2]; sum[3] += v[3];
    }
    int e = eh2 * 64 + ec;
    float bias = b3[e];
#pragma unroll
    for (int r = 0; r < 4; ++r) {
      int p = p4 + r;
      out[(((size_t)(i0 + (p >> 3))) * NRES + (j0 + (p & 7))) * CZ + e] =
          sum[r] + bias;
    }
  }
}

// ---------------- host launch ----------------
extern "C" void kernel_launch(void* const* d_in, const int* in_sizes, int n_in,
                              void* d_out, int out_size, void* d_ws, size_t ws_size,
                              hipStream_t stream) {
  const float* m = (const float*)d_in[0];
  const float* gamma = (const float*)d_in[1];
  const float* beta = (const float*)d_in[2];
  const float* W1 = (const float*)d_in[3];
  const float* W2 = (const float*)d_in[4];
  const float* W3 = (const float*)d_in[5];
  const float* b3 = (const float*)d_in[6];
  float* out = (float*)d_out;

  unsigned short* aT = (unsigned short*)d_ws;                 // k-slice-major
  unsigned short* bT = aT + (size_t)MDIM * S_DEPTH;
  unsigned short* W3T = bT + (size_t)MDIM * S_DEPTH;          // kq-major

  k_pre<<<400, 256, 0, stream>>>(m, gamma, beta, W1, W2, W3, aT, bT, W3T);
  k_opm<<<2304, 512, 0, stream>>>(aT, bT, W3T, b3, out);
}

// Round 7
// 217.888 us; speedup vs baseline: 1.2059x; 1.2059x over previous
//
#include <hip/hip_runtime.h>

#define S_DEPTH 256
#define NRES 384
#define CIN 32
#define CZ 128
#define MDIM (NRES * CIN) /* 12288 */

typedef short bf16x8 __attribute__((ext_vector_type(8)));
typedef short short4v __attribute__((ext_vector_type(4)));
typedef float f32x4 __attribute__((ext_vector_type(4)));

static __device__ __forceinline__ unsigned short f2bf(float f) {
  unsigned int u = __float_as_uint(f);
  unsigned int r = (u + 0x7fffu + ((u >> 16) & 1u)) >> 16; // RNE
  return (unsigned short)r;
}

static __device__ __forceinline__ void gld16(const void* g, void* l) {
  __builtin_amdgcn_global_load_lds((__attribute__((address_space(1))) void*)(g),
                                   (__attribute__((address_space(3))) void*)(l),
                                   16, 0, 0);
}

// ---------------- k_pre v3: LN + projections via MFMA ----------------------
// R7 theory: both prior k_pre variants had wave-UNIFORM W1/W2 addresses ->
// compiler scalarizes to s_load chains; per-CU chain volume identical in both
// (explains the invariant ~90us gap). Replace the 2048 VALU FMAs + uniform W
// fetches with one 16x16x32 MFMA pass: [256x32 mn] x [32x64 W1|W2].
// Layouts (verified by k_opm epilogue on HW): A row=l&15,k=(l>>4)*8+j;
// B col=l&15,k same; C col=l&15,row=(l>>4)*4+reg.
__global__ __launch_bounds__(256) void k_pre(
    const float* __restrict__ mm, const float* __restrict__ gamma,
    const float* __restrict__ beta, const float* __restrict__ W1,
    const float* __restrict__ W2, const float* __restrict__ W3,
    unsigned short* __restrict__ aT, unsigned short* __restrict__ bT,
    unsigned short* __restrict__ W3T) {
  __shared__ __align__(16) char sraw[256 * 33 * 4];      // f32 LN buf [256][33]
  __shared__ __align__(16) char mn_raw[256 * 80];        // bf16 mn, row stride 80B
  const int t = threadIdx.x;

  if (blockIdx.x < 16) {
    unsigned short (*tile)[72] = (unsigned short(*)[72])sraw; // [128][72]
    const int b = blockIdx.x;
    const int d0 = (b & 7) * 4;
    const int e0 = (b >> 3) * 64;
#pragma unroll
    for (int iter = 0; iter < 32; ++iter) {
      int lr_ = iter * 4 + (t >> 6);
      int c = lr_ >> 2, dl = lr_ & 3;
      int q = c * 32 + d0 + dl;
      tile[lr_][t & 63] = f2bf(W3[q * 128 + e0 + (t & 63)]);
    }
    __syncthreads();
    const int e_l = t >> 2;
    const int dl = t & 3;
    unsigned short* dst = W3T + (((size_t)(d0 + dl) * 128) + e0 + e_l) * 32;
#pragma unroll
    for (int j = 0; j < 32; ++j) dst[j] = tile[j * 4 + dl][e_l];
    return;
  }

  float* buf = (float*)sraw; // [256][33]
  const int i = blockIdx.x - 16;

#pragma unroll
  for (int it = 0; it < 8; ++it) {
    int s = it * 32 + (t >> 3);
    int c4 = (t & 7) * 4;
    const float4 v = *(const float4*)(mm + ((size_t)s * NRES + i) * CIN + c4);
    buf[s * 33 + c4 + 0] = v.x;
    buf[s * 33 + c4 + 1] = v.y;
    buf[s * 33 + c4 + 2] = v.z;
    buf[s * 33 + c4 + 3] = v.w;
  }
  __syncthreads();

  // LN for row t, write bf16 row into mn_lds (stride 80B: 5 coprime 8 ->
  // conflict-free at 16B granule for both these writes and the frag reads)
  {
    float x[32];
#pragma unroll
    for (int k = 0; k < 32; ++k) x[k] = buf[t * 33 + k];
    float mu = 0.f;
#pragma unroll
    for (int k = 0; k < 32; ++k) mu += x[k];
    mu *= (1.f / 32.f);
    float var = 0.f;
#pragma unroll
    for (int k = 0; k < 32; ++k) {
      float dk = x[k] - mu;
      var += dk * dk;
    }
    var *= (1.f / 32.f);
    float inv = rsqrtf(var + 1e-5f);
    char* row = mn_raw + t * 80;
#pragma unroll
    for (int q = 0; q < 4; ++q) {
      bf16x8 pk;
#pragma unroll
      for (int j = 0; j < 8; ++j) {
        int k = q * 8 + j;
        pk[j] = (short)f2bf((x[k] - mu) * inv * gamma[k] + beta[k]);
      }
      *(bf16x8*)(row + q * 16) = pk;
    }
  }

  // B-fragments: lane (quad=l>>4, lr=l&15): col=lr(+16), k=quad*8+j.
  // Lane-varying vector-ish loads (64B coalesced per j across lr), once/block.
  const int l = t & 63;
  const int w = t >> 6;       // wave = k-slice (64 s-rows each)
  const int lr = l & 15;
  const int quad = l >> 4;

  bf16x8 bfr[4];
#pragma unroll
  for (int nf = 0; nf < 4; ++nf) {
    const float* W = (nf < 2) ? W1 : W2;
    const int c = lr + (nf & 1) * 16;
#pragma unroll
    for (int j = 0; j < 8; ++j)
      bfr[nf][j] = (short)f2bf(W[(quad * 8 + j) * 32 + c]);
  }

  __syncthreads();

  // A-fragments from mn_lds and 16 MFMAs per wave
  f32x4 acc[4][4];
#pragma unroll
  for (int st = 0; st < 4; ++st) {
    const bf16x8 afr =
        *(const bf16x8*)(mn_raw + (size_t)(w * 64 + st * 16 + lr) * 80 + quad * 16);
#pragma unroll
    for (int nf = 0; nf < 4; ++nf) {
      f32x4 z = {0.f, 0.f, 0.f, 0.f};
      acc[st][nf] = __builtin_amdgcn_mfma_f32_16x16x32_bf16(afr, bfr[nf], z, 0, 0, 0);
    }
  }

  // store: aT/bT[(w*MDIM + i*32 + c)*64 + s_local], s_local = st*16+quad*4+r
#pragma unroll
  for (int st = 0; st < 4; ++st)
#pragma unroll
    for (int nf = 0; nf < 4; ++nf) {
      const int c = lr + (nf & 1) * 16;
      unsigned short* tgt = (nf < 2) ? aT : bT;
      short4v pk;
      pk[0] = (short)f2bf(acc[st][nf][0]);
      pk[1] = (short)f2bf(acc[st][nf][1]);
      pk[2] = (short)f2bf(acc[st][nf][2]);
      pk[3] = (short)f2bf(acc[st][nf][3]);
      *(short4v*)(tgt + ((size_t)w * MDIM + (size_t)i * 32 + c) * 64 + st * 16 + quad * 4) = pk;
    }
}

// ---------------- kernel 2: EXACT R4 winner (137.8us verified) --------------
__global__ __launch_bounds__(512, 2) void k_opm(
    const unsigned short* __restrict__ aT, const unsigned short* __restrict__ bT,
    const unsigned short* __restrict__ W3T, const float* __restrict__ b3,
    float* __restrict__ out) {
  __shared__ __align__(16) char smem[131072]; // 2x(A32K+B32K) staging; o_lds 128KB
  const int t = threadIdx.x;
  const int w = t >> 6;  // wave 0..7
  const int l = t & 63;
  const int lr = l & 15;
  const int quad = l >> 4;
  const int wm = w >> 2, wn = w & 3;

  const int g = blockIdx.x;
  const int xcd = g & 7;
  const int rr = g >> 3;                   // 0..287
  const int bx = rr / 6;                   // 0..47
  const int by = xcd * 6 + (rr - bx * 6);  // 0..47
  const int m0 = by * 256;
  const int n0 = bx * 256;

  f32x4 acc[8][4];
#pragma unroll
  for (int mt = 0; mt < 8; ++mt)
#pragma unroll
    for (int nt = 0; nt < 4; ++nt) {
      acc[mt][nt][0] = 0.f; acc[mt][nt][1] = 0.f;
      acc[mt][nt][2] = 0.f; acc[mt][nt][3] = 0.f;
    }

  // lane offset inside a 1KB chunk (8 rows x 128B), XOR k-seg swizzle
  const int laneoff = (l >> 3) * 64 + (((l & 7) ^ (l >> 3)) * 8);
  const int r8 = lr & 7;

  // ---- 2-phase pipelined main loop over 4 k-slices of 64 ----
  {
    const unsigned short* aS = aT + (size_t)m0 * 64;
    const unsigned short* bS = bT + (size_t)n0 * 64;
#pragma unroll
    for (int p_ = 0; p_ < 4; ++p_) {
      int ch = p_ * 8 + w;
      gld16(aS + ch * 512 + laneoff, smem + ch * 1024);
      gld16(bS + ch * 512 + laneoff, smem + 32768 + ch * 1024);
    }
  }
  __syncthreads();

  for (int kt = 0; kt < 4; ++kt) {
    if (kt < 3) {  // issue next-slice loads into the other buffer
      char* nb = smem + ((kt + 1) & 1) * 65536;
      const unsigned short* aS = aT + ((size_t)(kt + 1) * MDIM + m0) * 64;
      const unsigned short* bS = bT + ((size_t)(kt + 1) * MDIM + n0) * 64;
#pragma unroll
      for (int p_ = 0; p_ < 4; ++p_) {
        int ch = p_ * 8 + w;
        gld16(aS + ch * 512 + laneoff, nb + ch * 1024);
        gld16(bS + ch * 512 + laneoff, nb + 32768 + ch * 1024);
      }
    }
    const char* cb = smem + (kt & 1) * 65536;
    const char* cbB = cb + 32768;

#pragma unroll
    for (int ks = 0; ks < 2; ++ks) {
      const int segoff = (((ks * 4 + quad) ^ r8) << 4);
      bf16x8 af[8];
#pragma unroll
      for (int mt = 0; mt < 8; ++mt) {
        int chunk = wm * 16 + mt * 2 + (lr >> 3);
        af[mt] = *(const bf16x8*)(cb + chunk * 1024 + r8 * 128 + segoff);
      }
#pragma unroll
      for (int nt = 0; nt < 4; ++nt) {
        int chunk = wn * 8 + nt * 2 + (lr >> 3);
        bf16x8 bfr = *(const bf16x8*)(cbB + chunk * 1024 + r8 * 128 + segoff);
#pragma unroll
        for (int mt = 0; mt < 8; ++mt)
          acc[mt][nt] =
              __builtin_amdgcn_mfma_f32_16x16x32_bf16(af[mt], bfr, acc[mt][nt], 0, 0, 0);
      }
    }
    __syncthreads();  // next-tile DMA has the full compute phase to land
  }

  // ---- repack o (bf16, /256) into o_lds[64 p][1024 q'] XOR-swizzled ----
  const float scale = 1.0f / 256.0f;
#pragma unroll
  for (int mt = 0; mt < 8; ++mt) {
    int i_l = wm * 4 + (mt >> 1);
    int chc = 2 * (mt & 1) + (quad >> 1); // c0>>3, c0 = (mt&1)*16 + quad*4
#pragma unroll
    for (int nt = 0; nt < 4; ++nt) {
      int j_l = wn * 2 + (nt >> 1);
      int d = (nt & 1) * 16 + lr;
      int p = i_l * 8 + j_l;
      int ch = d * 4 + chc;
      int key = (p ^ d) & 7;
      int off = p * 2048 + ((ch ^ key) << 4) + 8 * (quad & 1);
      short4v pk;
      pk[0] = (short)f2bf(acc[mt][nt][0] * scale);
      pk[1] = (short)f2bf(acc[mt][nt][1] * scale);
      pk[2] = (short)f2bf(acc[mt][nt][2] * scale);
      pk[3] = (short)f2bf(acc[mt][nt][3] * scale);
      *(short4v*)(smem + off) = pk;
    }
  }
  __syncthreads();

  // ---- z[p][e] = sum_q' o[p][q'] * W3T ; wave w owns e-tile w (16 e) ----
  f32x4 zacc[4];
#pragma unroll
  for (int a = 0; a < 4; ++a) {
    zacc[a][0] = 0.f; zacc[a][1] = 0.f; zacc[a][2] = 0.f; zacc[a][3] = 0.f;
  }
  const float bias = b3[w * 16 + lr];

  // kq-major W3T: frag = W3T + (kq*128 + e)*32 + quad*8 ; kq step 4096 shorts
  const unsigned short* wg = W3T + (size_t)(w * 16 + lr) * 32 + quad * 8;

  bf16x8 wcur = *(const bf16x8*)(wg);
#pragma unroll
  for (int kq = 0; kq < 32; ++kq) {
    bf16x8 wnxt;
    if (kq < 31) wnxt = *(const bf16x8*)(wg + (size_t)(kq + 1) * 4096);
    bf16x8 aef[4];
#pragma unroll
    for (int mte = 0; mte < 4; ++mte) {
      int row = mte * 16 + lr;
      int ch = kq * 4 + quad;
      int key = (row ^ kq) & 7;
      aef[mte] = *(const bf16x8*)(smem + row * 2048 + ((ch ^ key) << 4));
    }
#pragma unroll
    for (int mte = 0; mte < 4; ++mte)
      zacc[mte] = __builtin_amdgcn_mfma_f32_16x16x32_bf16(aef[mte], wcur, zacc[mte], 0, 0, 0);
    wcur = wnxt;
  }

  const int i0 = by * 8, j0 = bx * 8;
  const int e = w * 16 + lr;
#pragma unroll
  for (int mte = 0; mte < 4; ++mte)
#pragma unroll
    for (int r = 0; r < 4; ++r) {
      int p = mte * 16 + quad * 4 + r;
      out[(((size_t)(i0 + (p >> 3))) * NRES + (j0 + (p & 7))) * CZ + e] =
          zacc[mte][r] + bias;
    }
}

// ---------------- host launch ----------------
extern "C" void kernel_launch(void* const* d_in, const int* in_sizes, int n_in,
                              void* d_out, int out_size, void* d_ws, size_t ws_size,
                              hipStream_t stream) {
  const float* m = (const float*)d_in[0];
  const float* gamma = (const float*)d_in[1];
  const float* beta = (const float*)d_in[2];
  const float* W1 = (const float*)d_in[3];
  const float* W2 = (const float*)d_in[4];
  const float* W3 = (const float*)d_in[5];
  const float* b3 = (const float*)d_in[6];
  float* out = (float*)d_out;

  unsigned short* aT = (unsigned short*)d_ws;                 // k-slice-major
  unsigned short* bT = aT + (size_t)MDIM * S_DEPTH;
  unsigned short* W3T = bT + (size_t)MDIM * S_DEPTH;          // kq-major

  k_pre<<<400, 256, 0, stream>>>(m, gamma, beta, W1, W2, W3, aT, bT, W3T);
  k_opm<<<2304, 512, 0, stream>>>(aT, bT, W3T, b3, out);
}